// Round 1
// baseline (968.817 us; speedup 1.0000x reference)
//
#include <hip/hip_runtime.h>
#include <math.h>

#define INC   128
#define HID   32
#define NSEG  16

// Order-preserving float <-> uint mapping so unsigned atomicMax works for
// float max (handles negatives; encode(any real) >= 0x007FFFFF > 0, so a
// zero-initialized accumulator is a valid identity).
__device__ __forceinline__ unsigned f2ord(float f) {
    unsigned u = __float_as_uint(f);
    return (u & 0x80000000u) ? ~u : (u | 0x80000000u);
}
__device__ __forceinline__ float ord2f(unsigned u) {
    return (u & 0x80000000u) ? __uint_as_float(u & 0x7fffffffu)
                             : __uint_as_float(~u);
}

__device__ __forceinline__ void flush_lds(int seg, int c4, const float4& sm,
                                          const float4& mx, float cnt,
                                          float* s_sum, unsigned* s_max, float* s_cnt) {
    int base = seg * INC + c4 * 4;
    atomicAdd(&s_sum[base + 0], sm.x);
    atomicAdd(&s_sum[base + 1], sm.y);
    atomicAdd(&s_sum[base + 2], sm.z);
    atomicAdd(&s_sum[base + 3], sm.w);
    atomicMax(&s_max[base + 0], f2ord(mx.x));
    atomicMax(&s_max[base + 1], f2ord(mx.y));
    atomicMax(&s_max[base + 2], f2ord(mx.z));
    atomicMax(&s_max[base + 3], f2ord(mx.w));
    if (c4 == 0) atomicAdd(&s_cnt[seg], cnt);
}

// ---------------- Kernel 1: segment sum / max / count -----------------------
// batch_idx is SORTED: each block's contiguous row chunk spans ~1-2 segments,
// so per-thread register accumulation flushes to LDS ~once, and the block
// does ~128*nseg global atomics total.
__global__ __launch_bounds__(256) void seg_reduce_kernel(
    const float4* __restrict__ feats4, const int* __restrict__ bidx,
    float* __restrict__ gsum, unsigned* __restrict__ gmax,
    float* __restrict__ gcnt, int nrows)
{
    __shared__ float    s_sum[NSEG * INC];
    __shared__ unsigned s_max[NSEG * INC];
    __shared__ float    s_cnt[NSEG];

    const int tid   = threadIdx.x;
    const int chunk = (nrows + gridDim.x - 1) / gridDim.x;
    const int start = blockIdx.x * chunk;
    if (start >= nrows) return;                    // uniform per block
    const int end = min(start + chunk, nrows);

    for (int i = tid; i < NSEG * INC; i += 256) { s_sum[i] = 0.f; s_max[i] = 0u; }
    if (tid < NSEG) s_cnt[tid] = 0.f;
    __syncthreads();

    const int c4   = tid & 31;   // which float4 of the row (0..31)
    const int slot = tid >> 5;   // row slot (0..7): 8 rows per iteration
    int    cur = -1;
    float4 sm  = make_float4(0.f, 0.f, 0.f, 0.f);
    float4 mx  = make_float4(0.f, 0.f, 0.f, 0.f);
    float  cnt = 0.f;

    for (int r = start + slot; r < end; r += 8) {
        int    seg = bidx[r];
        float4 f   = feats4[(size_t)r * (INC / 4) + c4];
        if (seg != cur) {
            if (cur >= 0) flush_lds(cur, c4, sm, mx, cnt, s_sum, s_max, s_cnt);
            cur = seg; sm = f; mx = f; cnt = 1.f;
        } else {
            sm.x += f.x; sm.y += f.y; sm.z += f.z; sm.w += f.w;
            mx.x = fmaxf(mx.x, f.x); mx.y = fmaxf(mx.y, f.y);
            mx.z = fmaxf(mx.z, f.z); mx.w = fmaxf(mx.w, f.w);
            cnt += 1.f;
        }
    }
    if (cur >= 0) flush_lds(cur, c4, sm, mx, cnt, s_sum, s_max, s_cnt);
    __syncthreads();

    // Global flush: only segments present in [start, end) (sorted => a range).
    const int sf = bidx[start];
    const int sl = bidx[end - 1];
    for (int s = sf; s <= sl; s++) {
        if (tid < INC) {
            atomicAdd(&gsum[s * INC + tid], s_sum[s * INC + tid]);
            atomicMax(&gmax[s * INC + tid], s_max[s * INC + tid]);
        }
        if (tid == 0) atomicAdd(&gcnt[s], s_cnt[s]);
    }
}

// ---------------- Kernel 2: tiny MLPs + sigmoid -> gate[16][128] ------------
// gate = sigmoid(mlp(mean) + mlp(max)); note b2 appears TWICE.
__global__ __launch_bounds__(256) void mlp_kernel(
    const float* __restrict__ gsum, const unsigned* __restrict__ gmax,
    const float* __restrict__ gcnt,
    const float* __restrict__ W1, const float* __restrict__ b1,
    const float* __restrict__ W2, const float* __restrict__ b2,
    float* __restrict__ gate)
{
    __shared__ float s_mean[NSEG * INC];
    __shared__ float s_max [NSEG * INC];
    __shared__ float s_h   [NSEG * HID];   // relu(h_mean) + relu(h_max)
    const int tid = threadIdx.x;

    for (int i = tid; i < NSEG * INC; i += 256) {
        int   s = i >> 7;  // /INC
        float c = gcnt[s];
        s_mean[i] = gsum[i] / fmaxf(c, 1.f);
        s_max[i]  = (c > 0.f) ? ord2f(gmax[i]) : 0.f;  // empty-segment guard
    }
    __syncthreads();

    for (int i = tid; i < NSEG * HID; i += 256) {
        int s = i / HID, h = i % HID;
        float am = b1[h], ax = b1[h];
        for (int c = 0; c < INC; c++) {
            float w = W1[c * HID + h];               // W1 is [INC][HID]
            am += s_mean[s * INC + c] * w;
            ax += s_max [s * INC + c] * w;
        }
        s_h[i] = fmaxf(am, 0.f) + fmaxf(ax, 0.f);
    }
    __syncthreads();

    for (int i = tid; i < NSEG * INC; i += 256) {
        int s = i >> 7, c = i & (INC - 1);
        float a = 2.f * b2[c];                       // b2 added in BOTH mlps
        for (int h = 0; h < HID; h++) a += s_h[s * HID + h] * W2[h * INC + c];
        gate[i] = 1.f / (1.f + expf(-a));
    }
}

// ---------------- Kernel 3: out = feats * gate[batch_idx] -------------------
__global__ __launch_bounds__(256) void apply_kernel(
    const float4* __restrict__ feats4, const int* __restrict__ bidx,
    const float4* __restrict__ gate4, float4* __restrict__ out4, int nrows)
{
    __shared__ float4 s_gate[NSEG * (INC / 4)];      // 8 KB, LDS-guaranteed hit
    for (int i = threadIdx.x; i < NSEG * (INC / 4); i += blockDim.x)
        s_gate[i] = gate4[i];
    __syncthreads();

    const int total = nrows * (INC / 4);
    for (int idx = blockIdx.x * blockDim.x + threadIdx.x; idx < total;
         idx += gridDim.x * blockDim.x) {
        int    r   = idx >> 5;                        // / (INC/4)
        int    c4  = idx & 31;
        int    seg = bidx[r];
        float4 f   = feats4[idx];
        float4 g   = s_gate[seg * (INC / 4) + c4];
        out4[idx]  = make_float4(f.x * g.x, f.y * g.y, f.z * g.z, f.w * g.w);
    }
}

extern "C" void kernel_launch(void* const* d_in, const int* in_sizes, int n_in,
                              void* d_out, int out_size, void* d_ws, size_t ws_size,
                              hipStream_t stream) {
    const float* feats = (const float*)d_in[0];
    const int*   bidx  = (const int*)d_in[1];
    const float* W1    = (const float*)d_in[2];
    const float* b1    = (const float*)d_in[3];
    const float* W2    = (const float*)d_in[4];
    const float* b2    = (const float*)d_in[5];
    float*       out   = (float*)d_out;
    const int nrows    = in_sizes[1];                 // N from batch_idx

    // Workspace layout (ws is re-poisoned to 0xAA each call -> must memset):
    //   [0,      8192)  gsum  float[16*128]
    //   [8192,  16384)  gmax  uint [16*128]  (order-mapped)
    //   [16384, 16448)  gcnt  float[16]
    //   [16448, 24640)  gate  float[16*128]  (16B-aligned for float4)
    char*     ws   = (char*)d_ws;
    float*    gsum = (float*)(ws);
    unsigned* gmax = (unsigned*)(ws + 8192);
    float*    gcnt = (float*)(ws + 16384);
    float*    gate = (float*)(ws + 16448);

    hipMemsetAsync(d_ws, 0, 16448, stream);           // zero accumulators only

    seg_reduce_kernel<<<2048, 256, 0, stream>>>(
        (const float4*)feats, bidx, gsum, gmax, gcnt, nrows);
    mlp_kernel<<<1, 256, 0, stream>>>(gsum, gmax, gcnt, W1, b1, W2, b2, gate);
    apply_kernel<<<8192, 256, 0, stream>>>(
        (const float4*)feats, bidx, (const float4*)gate, (float4*)out, nrows);
}